// Round 1
// baseline (1291.744 us; speedup 1.0000x reference)
//
#include <hip/hip_runtime.h>

// Problem constants (from reference setup_inputs)
#define B 2
#define C 64
#define H 192
#define W 320
#define D 32
#define EPS 1e-12f

// ---------------------------------------------------------------------------
// Pass 1: per-pixel channel reductions.
//   num[b,h,w,d] = sum_c q[b,c,h,w] * wf[b,c,h,w,d]
//   kk [b,h,w,d] = sum_c wf[b,c,h,w,d]^2
//   qq [b,h,w]   = sum_c q[b,c,h,w]^2
// Block: 256 threads = 32 consecutive w pixels x 8 d-quads (float4 per thread).
// wf read exactly once, fully coalesced (16B/lane).
// ---------------------------------------------------------------------------
__global__ __launch_bounds__(256) void dav_pass1(
    const float* __restrict__ q, const float* __restrict__ wf,
    float* __restrict__ num, float* __restrict__ kk, float* __restrict__ qq) {
  const int t  = threadIdx.x;
  const int p  = t >> 3;   // pixel within 32-wide tile
  const int dq = t & 7;    // d-quad index (d = 4*dq)
  const int w  = blockIdx.x * 32 + p;
  const int h  = blockIdx.y;
  const int b  = blockIdx.z;

  const long qbase = (((long)b * C) * H + h) * (long)W + w;  // q[b,0,h,w]
  const long qs    = (long)H * W;                            // c-stride in q
  const long ks    = ((long)H * W * D) / 4;                  // c-stride in wf, float4 units

  const float*  qp = q + qbase;
  const float4* kp = (const float4*)(wf + qbase * (long)D + (long)dq * 4);

  float4 nacc = make_float4(0.f, 0.f, 0.f, 0.f);
  float4 kacc = make_float4(0.f, 0.f, 0.f, 0.f);
  float  qacc = 0.f;

#pragma unroll 8
  for (int c = 0; c < C; ++c) {
    const float  qv = qp[(long)c * qs];
    const float4 kv = kp[(long)c * ks];
    nacc.x += qv * kv.x;  nacc.y += qv * kv.y;
    nacc.z += qv * kv.z;  nacc.w += qv * kv.w;
    kacc.x += kv.x * kv.x;  kacc.y += kv.y * kv.y;
    kacc.z += kv.z * kv.z;  kacc.w += kv.w * kv.w;
    qacc += qv * qv;
  }

  const long o = ((((long)b * H + h) * W) + w) * (long)D + (long)dq * 4;
  *(float4*)(num + o) = nacc;
  *(float4*)(kk + o)  = kacc;
  if (dq == 0) qq[((long)b * H + h) * W + w] = qacc;
}

// ---------------------------------------------------------------------------
// Pass 2: 3x3 zero-padded box filter + normalize.
// Tile: TH x TW output pixels, all D per block. LDS halo tile, D padded to 33
// to avoid bank conflicts for the (w in lanes, fixed d) read pattern.
// Output written [B,D,H,W], coalesced along w.
// ---------------------------------------------------------------------------
#define TH 2
#define TW 32

__global__ __launch_bounds__(256) void dav_pass2(
    const float* __restrict__ num, const float* __restrict__ kk,
    const float* __restrict__ qq, float* __restrict__ out) {
  __shared__ float sn[TH + 2][TW + 2][33];
  __shared__ float sk[TH + 2][TW + 2][33];
  __shared__ float sq[TH + 2][TW + 2];

  const int t  = threadIdx.x;
  const int b  = blockIdx.z;
  const int h0 = blockIdx.y * TH;
  const int w0 = blockIdx.x * TW;

  // Fill LDS halo tile (zero padding outside the image).
  const int NF = (TH + 2) * (TW + 2) * D;  // 4*34*32 = 4352
  for (int l = t; l < NF; l += 256) {
    const int d   = l & (D - 1);
    const int rem = l >> 5;
    const int ww  = rem % (TW + 2);
    const int hh  = rem / (TW + 2);
    const int gh  = h0 - 1 + hh;
    const int gw  = w0 - 1 + ww;
    float nv = 0.f, kv = 0.f;
    if (gh >= 0 && gh < H && gw >= 0 && gw < W) {
      const long o = (((long)b * H + gh) * W + gw) * (long)D + d;
      nv = num[o];
      kv = kk[o];
    }
    sn[hh][ww][d] = nv;
    sk[hh][ww][d] = kv;
  }
  for (int l = t; l < (TH + 2) * (TW + 2); l += 256) {
    const int ww = l % (TW + 2);
    const int hh = l / (TW + 2);
    const int gh = h0 - 1 + hh;
    const int gw = w0 - 1 + ww;
    float v = 0.f;
    if (gh >= 0 && gh < H && gw >= 0 && gw < W)
      v = qq[((long)b * H + gh) * W + gw];
    sq[hh][ww] = v;
  }
  __syncthreads();

  const int w  = t & 31;   // lane-contiguous w for coalesced output writes
  const int dg = t >> 5;   // 0..7 -> d group of 4

  for (int hh = 0; hh < TH; ++hh) {
    // qq box for this pixel
    float qb = 0.f;
#pragma unroll
    for (int ih = 0; ih < 3; ++ih)
#pragma unroll
      for (int iw = 0; iw < 3; ++iw) qb += sq[hh + ih][w + iw];
    const float nqv = fmaxf(sqrtf(qb), EPS);

#pragma unroll
    for (int di = 0; di < 4; ++di) {
      const int d = dg * 4 + di;
      float nb = 0.f, kb = 0.f;
#pragma unroll
      for (int ih = 0; ih < 3; ++ih)
#pragma unroll
        for (int iw = 0; iw < 3; ++iw) {
          nb += sn[hh + ih][w + iw][d];
          kb += sk[hh + ih][w + iw][d];
        }
      const float nkv = fmaxf(sqrtf(kb), EPS);
      out[(((long)b * D + d) * H + (h0 + hh)) * W + w0 + w] = nb / (nqv * nkv);
    }
  }
}

// ---------------------------------------------------------------------------
// Fallback (only if workspace is too small): direct 3x3 gather. Slow, correct.
// ---------------------------------------------------------------------------
__global__ void dav_fallback(const float* __restrict__ q,
                             const float* __restrict__ wf,
                             float* __restrict__ out) {
  const long i = (long)blockIdx.x * 256 + threadIdx.x;
  const long n = (long)B * D * H * W;
  if (i >= n) return;
  const int w = (int)(i % W);
  long r = i / W;
  const int h = (int)(r % H);
  r /= H;
  const int d = (int)(r % D);
  const int b = (int)(r / D);

  float nb = 0.f, kb = 0.f, qb = 0.f;
  for (int ih = -1; ih <= 1; ++ih) {
    const int gh = h + ih;
    if (gh < 0 || gh >= H) continue;
    for (int iw = -1; iw <= 1; ++iw) {
      const int gw = w + iw;
      if (gw < 0 || gw >= W) continue;
      float nv = 0.f, kv2 = 0.f, qv2 = 0.f;
      for (int c = 0; c < C; ++c) {
        const long qi = (((long)b * C + c) * H + gh) * (long)W + gw;
        const float qv = q[qi];
        const float kv = wf[qi * D + d];
        nv  += qv * kv;
        kv2 += kv * kv;
        qv2 += qv * qv;
      }
      nb += nv;
      kb += kv2;
      qb += qv2;
    }
  }
  out[i] = nb / (fmaxf(sqrtf(qb), EPS) * fmaxf(sqrtf(kb), EPS));
}

extern "C" void kernel_launch(void* const* d_in, const int* in_sizes, int n_in,
                              void* d_out, int out_size, void* d_ws, size_t ws_size,
                              hipStream_t stream) {
  const float* q  = (const float*)d_in[0];
  const float* wf = (const float*)d_in[1];
  float* out = (float*)d_out;

  const size_t plane = (size_t)B * H * W;        // 122880
  const size_t full  = plane * D;                // 3932160
  const size_t need  = (2 * full + plane) * sizeof(float);  // ~30.5 MiB

  if (ws_size >= need) {
    float* num = (float*)d_ws;
    float* kk  = num + full;
    float* qq  = kk + full;
    dim3 g1(W / 32, H, B);
    dav_pass1<<<g1, 256, 0, stream>>>(q, wf, num, kk, qq);
    dim3 g2(W / TW, H / TH, B);
    dav_pass2<<<g2, 256, 0, stream>>>(num, kk, qq, out);
  } else {
    const long n = (long)B * D * H * W;
    dav_fallback<<<(int)((n + 255) / 256), 256, 0, stream>>>(q, wf, out);
  }
}